// Round 11
// baseline (922.025 us; speedup 1.0000x reference)
//
#include <hip/hip_runtime.h>

// ResidualVectorQuantizer on MI355X (gfx950) — XCD-grouped bf16-MFMA GEMM
// (128x128x32, 3-slot LDS ring, ONE barrier per K-step, stage-ahead +
// counted vmcnt(4), 0-conflict swizzle, 48KB LDS, 3 blocks/CU) + fused post
// (combine top-4 + margin + LDS-queued exact np-fp32 refine) + standalone
// streaming resupd + fused prep.
// R9 lesson: never co-locate high-VGPR refine with TLP-hungry streaming.
// R6 lesson: 5 blocks/CU spills acc[4][4] (1 GB scratch).
// inputs:   d_in[0] = inputs    float32 [16,4096,512]  -> 65536 x 512
//           d_in[1] = codebooks float32 [4,1024,512]
// outputs (float32, concatenated flat):
//   [0 .. 33554431]          final_ste   (region doubles as scratch pre-finalize)
//   [33554432]               total_q_loss / 4
//   [33554433]               total_e_loss / 4
//   [33554434 .. +262143]    indices [4][16][4096] stored as float
// ws: [0,4MB) cb_bf16; [4MB,+64MB) res_bf16; [68MB,+16KB) cn32; +32B loss

#define NROWS 65536
#define DDIM  512
#define KC    1024

#define AS1 __attribute__((address_space(1)))
#define AS3 __attribute__((address_space(3)))

typedef __attribute__((ext_vector_type(8))) short short8v;
typedef __attribute__((ext_vector_type(4))) float f32x4;

__device__ __forceinline__ unsigned short f2bf(float f) {
  unsigned u = __float_as_uint(f);
  unsigned r = (u + 0x7FFFu + ((u >> 16) & 1u)) >> 16;
  return (unsigned short)r;
}

__device__ __forceinline__ bool lexlt(float v1, int i1, float v2, int i2) {
  return (v1 < v2) || (v1 == v2 && i1 < i2);
}

__device__ __forceinline__ void merge3(float& v0, float& v1, float& v2,
                                       float m0, float m1, float m2) {
  float x1 = fmaxf(v0, m0); v0 = fminf(v0, m0);
  float y = fminf(v1, m1), z = fmaxf(v1, m1);
  float nv1 = fminf(x1, y);
  v2 = fminf(fmaxf(x1, y), fminf(z, fminf(v2, m2)));
  v1 = nv1;
}

__device__ __forceinline__ void top3of4(float k0, float k1, float k2, float k3,
                                        float& m0, float& m1, float& m2) {
  float a = fminf(k0, k1), b = fmaxf(k0, k1);
  float c = fminf(k2, k3), d = fmaxf(k2, k3);
  m0 = fminf(a, c);
  float f = fmaxf(a, c), g = fminf(b, d);
  m1 = fminf(f, g); m2 = fmaxf(f, g);
}

// compiler-fence-wrapped workgroup barrier: raw s_barrier (no implicit
// vmcnt/lgkmcnt drain) with "memory" clobbers pinning LDS/global ops.
__device__ __forceinline__ void wg_barrier() {
  asm volatile("" ::: "memory");
  __builtin_amdgcn_s_barrier();
  asm volatile("" ::: "memory");
}

// ---------------- fused prep: cnorm + codebook cvt + initial residual ------
__global__ void __launch_bounds__(256)
prep_kernel(const float* __restrict__ cbs, float* __restrict__ cn32,
            const float4* __restrict__ x4, ushort4* __restrict__ cbb4,
            ushort4* __restrict__ res4) {
  const int code = blockIdx.x;           // 0..4095
  const int l = threadIdx.x;
  if (l < 32) {
    const int b = l >> 3, j = l & 7;
    const float* p = cbs + (size_t)code * DDIM + b * 128 + j;
    float racc;
    {
      #pragma clang fp contract(off)
      float x0 = p[0];
      racc = x0 * x0;
      for (int s = 1; s < 16; ++s) { float x = p[8 * s]; float sq = x * x; racc = racc + sq; }
    }
    {
      #pragma clang fp contract(off)
      float o;
      o = __shfl_xor(racc, 1, 64);  racc = racc + o;
      o = __shfl_xor(racc, 2, 64);  racc = racc + o;
      o = __shfl_xor(racc, 4, 64);  racc = racc + o;
      o = __shfl_xor(racc, 8, 64);  racc = racc + o;
      o = __shfl_xor(racc, 16, 64); racc = racc + o;
      if (l == 0) cn32[code] = racc;
    }
  }
  const float4* cb4 = (const float4*)cbs;
  for (long i = blockIdx.x * 256L + threadIdx.x; i < 524288L;
       i += (long)gridDim.x * 256) {
    float4 v = cb4[i];
    ushort4 o; o.x = f2bf(v.x); o.y = f2bf(v.y); o.z = f2bf(v.z); o.w = f2bf(v.w);
    cbb4[i] = o;
  }
  for (long i = blockIdx.x * 256L + threadIdx.x; i < 8388608L;
       i += (long)gridDim.x * 256) {
    float4 v = x4[i];
    ushort4 o; o.x = f2bf(v.x); o.y = f2bf(v.y); o.z = f2bf(v.z); o.w = f2bf(v.w);
    res4[i] = o;
  }
}

// residual update, one WAVE per row: res = bf16( x - sum_{l<nlev} cb[idx_l] ),
// exact fp32 chain; indices read once per row (wave-uniform). Low-VGPR
// streaming kernel — keep separate from the high-VGPR refine (R9 lesson).
__global__ void __launch_bounds__(256)
resupd_kernel(const float4* __restrict__ x4, const float* __restrict__ cbs,
              const float* __restrict__ idx_f, ushort4* __restrict__ res4,
              int nlev) {
  const int gwave = (blockIdx.x * 256 + threadIdx.x) >> 6;
  const int lane  = threadIdx.x & 63;
  const int nwaves = gridDim.x * 4;
  const float4* cb4 = (const float4*)cbs;
  for (int row = gwave; row < NROWS; row += nwaves) {
    int ci[4];
    for (int l = 0; l < nlev; ++l) ci[l] = (int)idx_f[(size_t)l * NROWS + row];
    #pragma unroll
    for (int half = 0; half < 2; ++half) {
      const int p = half * 64 + lane;
      float4 v = x4[(size_t)row * 128 + p];
      for (int l = 0; l < nlev; ++l) {
        const float4 c = cb4[((size_t)(l * KC + ci[l])) * 128 + p];
        v.x -= c.x; v.y -= c.y; v.z -= c.z; v.w -= c.w;
      }
      ushort4 o; o.x = f2bf(v.x); o.y = f2bf(v.y); o.z = f2bf(v.z); o.w = f2bf(v.w);
      res4[(size_t)row * 128 + p] = o;
    }
  }
}

// ---------------- score GEMM (128x128x32, 3-slot ring, 1 barrier/step) -----
// Grid 4096 = 512 rowTiles x 8 colTiles; 8 blocks sharing an A-panel land on
// the same XCD. Per K-step: STG(ks+1 -> slot (ks+1)%3), vmcnt(4) [tile ks
// landed — every wave's own loads, each BEFORE its barrier arrival, so all
// waves' loads landed before any wave passes the barrier], ONE s_barrier,
// ds_read slot ks%3, 16 MFMA. Ring safety: STG at step ks overwrites slot
// (ks+1)%3 = (ks-2)%3, last read at step ks-2; every wave's step-(ks-2)
// reads completed before its own MFMA, which precedes its BARRIER_{ks-2}
// arrival, and the staging wave is at most one barrier-interval ahead — so
// the overwrite is race-free with a single barrier per step. Swizzle proven
// 0-conflict (R4). 48KB LDS -> 3 blocks/CU (12 waves): trades 4 waves of
// TLP for halving the per-step barrier count (33 -> 17 per block).
template <int LVL>
__global__ void __launch_bounds__(256, 3)
score_gemm(const ushort* __restrict__ res, const ushort* __restrict__ cbb,
           const float* __restrict__ cn32, float* __restrict__ partials) {
  __shared__ ushort lds[24576];   // 48 KB: slot s = A @s*8192, B @s*8192+4096

  const int t = threadIdx.x;
  const int w = t >> 6, lane = t & 63;
  const int fr = lane & 15, kg = lane >> 4;
  const int rh = w >> 1, ch = w & 1;
  const int xcd = blockIdx.x & 7;
  const int j   = blockIdx.x >> 3;
  const int colTile = j & 7;
  const int rowTile = xcd * 64 + (j >> 3);
  const int row0 = rowTile * 128;

  const ushort* Asrc = res + (size_t)row0 * DDIM;
  const ushort* Bsrc = cbb + ((size_t)LVL * KC + colTile * 128) * DDIM;

  const int r0s = t >> 2, kq = t & 3;
  const int r1s = 64 + r0s;
  const int swz = (t >> 3) & 3;
  const size_t off0 = (size_t)r0s * DDIM + (size_t)((kq ^ swz) * 8);
  const size_t off1 = (size_t)r1s * DDIM + (size_t)((kq ^ swz) * 8);
  const int kgs = (kg ^ ((fr >> 1) & 3)) * 8;

  f32x4 acc[4][4];
  #pragma unroll
  for (int ri = 0; ri < 4; ++ri)
    #pragma unroll
    for (int ci = 0; ci < 4; ++ci) { f32x4 z = {0.f, 0.f, 0.f, 0.f}; acc[ri][ci] = z; }

#define STG(KS, S)                                                            \
  do {                                                                        \
    __builtin_amdgcn_global_load_lds(                                         \
        (const AS1 unsigned*)(Asrc + off0 + (KS) * 32),                       \
        (AS3 unsigned*)&lds[(S) * 8192 + w * 512], 16, 0, 0);                 \
    __builtin_amdgcn_global_load_lds(                                         \
        (const AS1 unsigned*)(Asrc + off1 + (KS) * 32),                       \
        (AS3 unsigned*)&lds[(S) * 8192 + 2048 + w * 512], 16, 0, 0);          \
    __builtin_amdgcn_global_load_lds(                                         \
        (const AS1 unsigned*)(Bsrc + off0 + (KS) * 32),                       \
        (AS3 unsigned*)&lds[(S) * 8192 + 4096 + w * 512], 16, 0, 0);          \
    __builtin_amdgcn_global_load_lds(                                         \
        (const AS1 unsigned*)(Bsrc + off1 + (KS) * 32),                       \
        (AS3 unsigned*)&lds[(S) * 8192 + 6144 + w * 512], 16, 0, 0);          \
  } while (0)

  STG(0, 0);
  #pragma unroll
  for (int ks = 0; ks < 16; ++ks) {
    const int s = ks % 3;
    if (ks < 15) {
      STG(ks + 1, (ks + 1) % 3);
      asm volatile("s_waitcnt vmcnt(4)" ::: "memory");  // tile ks landed;
                                                        // tile ks+1 in flight
    } else {
      asm volatile("s_waitcnt vmcnt(0)" ::: "memory");  // last tile: drain
    }
    wg_barrier();   // the ONLY barrier this K-step
    short8v a[4], b[4];
    #pragma unroll
    for (int i = 0; i < 4; ++i)
      a[i] = *(const short8v*)&lds[s * 8192 + (rh * 64 + i * 16 + fr) * 32 + kgs];
    #pragma unroll
    for (int i = 0; i < 4; ++i)
      b[i] = *(const short8v*)&lds[s * 8192 + 4096 + (ch * 64 + i * 16 + fr) * 32 + kgs];
    __builtin_amdgcn_s_setprio(1);
    #pragma unroll
    for (int ri = 0; ri < 4; ++ri)
      #pragma unroll
      for (int ci = 0; ci < 4; ++ci)
        acc[ri][ci] = __builtin_amdgcn_mfma_f32_16x16x32_bf16(
            a[ri], b[ci], acc[ri][ci], 0, 0, 0);
    __builtin_amdgcn_s_setprio(0);
  }
#undef STG
  __syncthreads();   // all waves' final reads done; LDS reusable for epilogue

  // ---- epilogue: scores -> packed keys -> per-row top-3 over 128 cols ----
  float* hT = (float*)lds;                 // [2 rh][2 ch][64][3] = 3 KB alias
  float cnv[4];
  #pragma unroll
  for (int ci = 0; ci < 4; ++ci)
    cnv[ci] = cn32[LVL * KC + colTile * 128 + ch * 64 + ci * 16 + fr] + 0.25f;

  #pragma unroll
  for (int ri = 0; ri < 4; ++ri) {
    #pragma unroll
    for (int j2 = 0; j2 < 4; ++j2) {
      float k[4];
      #pragma unroll
      for (int ci = 0; ci < 4; ++ci) {
        float s = fmaf(-2.0f, acc[ri][ci][j2], cnv[ci]);   // score + 0.25
        unsigned col = (unsigned)(colTile * 128 + ch * 64 + ci * 16 + fr);
        unsigned u = (__float_as_uint(s) & 0xFFFFFC00u) | col;
        k[ci] = __uint_as_float(u);
      }
      float m0, m1, m2;
      top3of4(k[0], k[1], k[2], k[3], m0, m1, m2);
      #pragma unroll
      for (int m = 1; m <= 8; m <<= 1) {
        float t0 = __shfl_xor(m0, m, 64);
        float t1 = __shfl_xor(m1, m, 64);
        float t2 = __shfl_xor(m2, m, 64);
        merge3(m0, m1, m2, t0, t1, t2);
      }
      if (fr == 0) {
        int row64 = ri * 16 + kg * 4 + j2;
        hT[(((rh * 2 + ch) * 64) + row64) * 3 + 0] = m0;
        hT[(((rh * 2 + ch) * 64) + row64) * 3 + 1] = m1;
        hT[(((rh * 2 + ch) * 64) + row64) * 3 + 2] = m2;
      }
    }
  }
  __syncthreads();

  if (t < 128) {
    const int lrh = t >> 6, r64 = t & 63;
    float u0 = hT[(((lrh * 2 + 0) * 64) + r64) * 3 + 0];
    float u1 = hT[(((lrh * 2 + 0) * 64) + r64) * 3 + 1];
    float u2 = hT[(((lrh * 2 + 0) * 64) + r64) * 3 + 2];
    float s0 = hT[(((lrh * 2 + 1) * 64) + r64) * 3 + 0];
    float s1 = hT[(((lrh * 2 + 1) * 64) + r64) * 3 + 1];
    float s2 = hT[(((lrh * 2 + 1) * 64) + r64) * 3 + 2];
    merge3(u0, u1, u2, s0, s1, s2);
    const int grow = row0 + lrh * 64 + r64;
    partials[(size_t)(colTile * 3 + 0) * NROWS + grow] = u0;
    partials[(size_t)(colTile * 3 + 1) * NROWS + grow] = u1;
    partials[(size_t)(colTile * 3 + 2) * NROWS + grow] = u2;
  }
}

// ---------------- post: combine (top-4 + margin) + LDS-queued refine -------
// 256 blocks x 256 rows (R8 structure — measured best). High VGPR is fine
// here: per-block work is tiny and there is no streaming phase.
template <int LVL>
__global__ void __launch_bounds__(256)
post_kernel(const float* __restrict__ partials, const float* __restrict__ x,
            const float* __restrict__ cbs, const float* __restrict__ cn32,
            float* __restrict__ idx_io) {
  __shared__ int qlist[256];
  __shared__ int qcL[256][4];
  __shared__ int qn_l;
  const int t = threadIdx.x;
  if (t == 0) qn_l = 0;
  __syncthreads();

  // ---- phase 1: combine ----
  const int row = blockIdx.x * 256 + t;
  {
    float v0 = 3.4e38f, v1 = 3.4e38f, v2 = 3.4e38f, v3 = 3.4e38f;
    #pragma unroll
    for (int p = 0; p < 24; ++p) {
      const float kv = partials[(size_t)p * NROWS + row];
      const bool b3 = kv < v3, b2 = kv < v2, b1 = kv < v1, b0 = kv < v0;
      v3 = b3 ? (b2 ? v2 : kv) : v3;
      v2 = b2 ? (b1 ? v1 : kv) : v2;
      v1 = b1 ? (b0 ? v0 : kv) : v1;
      v0 = b0 ? kv : v0;
    }
    if (v1 - v0 > 1e-3f) {
      idx_io[(size_t)LVL * NROWS + row] = (float)(__float_as_uint(v0) & 1023u);
    } else {
      int pos = atomicAdd(&qn_l, 1);
      qlist[pos] = row;
      qcL[pos][0] = (int)(__float_as_uint(v0) & 1023u);
      qcL[pos][1] = (int)(__float_as_uint(v1) & 1023u);
      qcL[pos][2] = (int)(__float_as_uint(v2) & 1023u);
      qcL[pos][3] = (int)(__float_as_uint(v3) & 1023u);
    }
  }
  __syncthreads();

  // ---- phase 2: exact np-fp32 refine of queued rows ----
  const int qn = qn_l;
  const float4* x4  = (const float4*)x;
  const float4* cb4 = (const float4*)cbs;
  const float*  cnL = cn32 + LVL * KC;

  for (int base = 0; base < qn * 4; base += 256) {
    const int wi = base + t;
    if (wi < qn * 4) {
      const int qi = wi >> 2, cd = wi & 3;
      const int grow = qlist[qi];
      const int ci   = qcL[qi][cd];
      const float4* xr = x4 + (size_t)grow * 128;
      const float4* cq = cb4 + ((size_t)LVL * KC + ci) * 128;
      const float4* cl[LVL > 0 ? LVL : 1];
      #pragma unroll
      for (int l = 0; l < LVL; ++l)
        cl[l] = cb4 +
                ((size_t)(l * KC + (int)idx_io[(size_t)l * NROWS + grow])) * 128;

      float Bk[4];
      float dacc = 0.0f;
      #pragma unroll
      for (int b = 0; b < 4; ++b) {
        #pragma clang fp contract(off)
        float racc[8];
        for (int s = 0; s < 16; ++s) {
          const int q = b * 32 + s * 2;
          float4 v0 = xr[q], v1 = xr[q + 1];
          #pragma unroll
          for (int l = 0; l < LVL; ++l) {
            const float4 c0 = cl[l][q], c1 = cl[l][q + 1];
            v0.x -= c0.x; v0.y -= c0.y; v0.z -= c0.z; v0.w -= c0.w;
            v1.x -= c1.x; v1.y -= c1.y; v1.z -= c1.z; v1.w -= c1.w;
          }
          if (s == 0) {
            racc[0] = v0.x * v0.x; racc[1] = v0.y * v0.y;
            racc[2] = v0.z * v0.z; racc[3] = v0.w * v0.w;
            racc[4] = v1.x * v1.x; racc[5] = v1.y * v1.y;
            racc[6] = v1.z * v1.z; racc[7] = v1.w * v1.w;
          } else {
            float sq;
            sq = v0.x * v0.x; racc[0] = racc[0] + sq;
            sq = v0.y * v0.y; racc[1] = racc[1] + sq;
            sq = v0.z * v0.z; racc[2] = racc[2] + sq;
            sq = v0.w * v0.w; racc[3] = racc[3] + sq;
            sq = v1.x * v1.x; racc[4] = racc[4] + sq;
            sq = v1.y * v1.y; racc[5] = racc[5] + sq;
            sq = v1.z * v1.z; racc[6] = racc[6] + sq;
            sq = v1.w * v1.w; racc[7] = racc[7] + sq;
          }
          const float4 c0 = cq[q], c1 = cq[q + 1];
          dacc = fmaf(v0.x, c0.x, dacc); dacc = fmaf(v0.y, c0.y, dacc);
          dacc = fmaf(v0.z, c0.z, dacc); dacc = fmaf(v0.w, c0.w, dacc);
          dacc = fmaf(v1.x, c1.x, dacc); dacc = fmaf(v1.y, c1.y, dacc);
          dacc = fmaf(v1.z, c1.z, dacc); dacc = fmaf(v1.w, c1.w, dacc);
        }
        float t0 = (racc[0] + racc[1]) + (racc[2] + racc[3]);
        float t1 = (racc[4] + racc[5]) + (racc[6] + racc[7]);
        Bk[b] = t0 + t1;
      }
      float vfin;
      {
        #pragma clang fp contract(off)
        float Arow = (Bk[0] + Bk[1]) + (Bk[2] + Bk[3]);
        float ab = Arow + cnL[ci];
        vfin = ab - 2.0f * dacc;
      }
      // quad lex-min: lanes 4k..4k+3 hold cands 0..3 of row grow
      float bv = vfin; int bi = ci;
      float ov = __shfl_xor(bv, 1, 64); int oi = __shfl_xor(bi, 1, 64);
      if (lexlt(ov, oi, bv, bi)) { bv = ov; bi = oi; }
      ov = __shfl_xor(bv, 2, 64); oi = __shfl_xor(bi, 2, 64);
      if (lexlt(ov, oi, bv, bi)) { bv = ov; bi = oi; }
      if (cd == 0) idx_io[(size_t)LVL * NROWS + grow] = (float)bi;
    }
  }
}

// ---------------- finalize: one wave per row ----------------
__global__ void __launch_bounds__(256)
finalize_kernel(const float4* __restrict__ x4, const float* __restrict__ cbs,
                const float* __restrict__ idx_f, float4* __restrict__ out,
                double* __restrict__ loss_acc) {
  double ls0 = 0.0, ls1 = 0.0, ls2 = 0.0, ls3 = 0.0;
  const int gwave = (blockIdx.x * 256 + threadIdx.x) >> 6;
  const int lane  = threadIdx.x & 63;
  const int nwaves = gridDim.x * 4;
  const float4* cb4 = (const float4*)cbs;

  for (int row = gwave; row < NROWS; row += nwaves) {
    int ci[4];
    #pragma unroll
    for (int l = 0; l < 4; ++l) ci[l] = (int)idx_f[(size_t)l * NROWS + row];
    #pragma unroll
    for (int half = 0; half < 2; ++half) {
      const int p = half * 64 + lane;
      const float4 xv = x4[(size_t)row * 128 + p];
      float4 rr = xv;
      float4 tq = make_float4(0.f, 0.f, 0.f, 0.f);
      #pragma unroll
      for (int l = 0; l < 4; ++l) {
        const float4 qv = cb4[((size_t)(l * KC + ci[l])) * 128 + p];
        rr.x -= qv.x; rr.y -= qv.y; rr.z -= qv.z; rr.w -= qv.w;
        const double ss = (double)rr.x * rr.x + (double)rr.y * rr.y +
                          (double)rr.z * rr.z + (double)rr.w * rr.w;
        if      (l == 0) ls0 += ss;
        else if (l == 1) ls1 += ss;
        else if (l == 2) ls2 += ss;
        else             ls3 += ss;
        tq.x += qv.x; tq.y += qv.y; tq.z += qv.z; tq.w += qv.w;
      }
      float4 o;
      o.x = xv.x + (tq.x - xv.x);
      o.y = xv.y + (tq.y - xv.y);
      o.z = xv.z + (tq.z - xv.z);
      o.w = xv.w + (tq.w - xv.w);
      out[(size_t)row * 128 + p] = o;
    }
  }
  #pragma unroll
  for (int m = 1; m <= 32; m <<= 1) {
    ls0 += __shfl_xor(ls0, m, 64);
    ls1 += __shfl_xor(ls1, m, 64);
    ls2 += __shfl_xor(ls2, m, 64);
    ls3 += __shfl_xor(ls3, m, 64);
  }
  __shared__ double sred[4][4];
  const int wave = threadIdx.x >> 6;
  if ((threadIdx.x & 63) == 0) {
    sred[wave][0] = ls0; sred[wave][1] = ls1; sred[wave][2] = ls2; sred[wave][3] = ls3;
  }
  __syncthreads();
  if (threadIdx.x < 4) {
    const double v = sred[0][threadIdx.x] + sred[1][threadIdx.x] +
                     sred[2][threadIdx.x] + sred[3][threadIdx.x];
    atomicAdd(loss_acc + threadIdx.x, v);
  }
}

__global__ void write_losses_kernel(const double* __restrict__ loss_acc,
                                    float* __restrict__ out) {
  if (threadIdx.x == 0 && blockIdx.x == 0) {
    const double inv = 1.0 / (double)((size_t)NROWS * (size_t)DDIM);
    const double tv = (loss_acc[0] * inv + loss_acc[1] * inv +
                       loss_acc[2] * inv + loss_acc[3] * inv) * 0.25;
    out[33554432] = (float)tv;
    out[33554433] = (float)tv;
  }
}

extern "C" void kernel_launch(void* const* d_in, const int* in_sizes, int n_in,
                              void* d_out, int out_size, void* d_ws, size_t ws_size,
                              hipStream_t stream) {
  (void)in_sizes; (void)n_in; (void)out_size; (void)ws_size;
  const float* x   = (const float*)d_in[0];
  const float* cbs = (const float*)d_in[1];
  float* out_f     = (float*)d_out;
  float* idx_f     = out_f + 33554434;

  ushort* cbb  = (ushort*)d_ws;                               // 4 MB
  ushort* res  = (ushort*)((char*)d_ws + 4194304);            // 64 MB
  float*  cn32 = (float*)((char*)d_ws + 4194304 + 67108864);  // 16 KB
  double* loss = (double*)((char*)d_ws + 4194304 + 67108864 + 16384);

  // scratch carved from the ste region of d_out (unused until finalize)
  float* partials = out_f;                        // 24 * 65536 floats = 6 MB

  hipMemsetAsync(loss, 0, 4 * sizeof(double), stream);

  prep_kernel<<<4096, 256, 0, stream>>>(cbs, cn32, (const float4*)x,
                                        (ushort4*)cbb, (ushort4*)res);

  score_gemm<0><<<4096, 256, 0, stream>>>(res, cbb, cn32, partials);
  post_kernel<0><<<256, 256, 0, stream>>>(partials, x, cbs, cn32, idx_f);
  resupd_kernel<<<2048, 256, 0, stream>>>((const float4*)x, cbs, idx_f,
                                          (ushort4*)res, 1);

  score_gemm<1><<<4096, 256, 0, stream>>>(res, cbb, cn32, partials);
  post_kernel<1><<<256, 256, 0, stream>>>(partials, x, cbs, cn32, idx_f);
  resupd_kernel<<<2048, 256, 0, stream>>>((const float4*)x, cbs, idx_f,
                                          (ushort4*)res, 2);

  score_gemm<2><<<4096, 256, 0, stream>>>(res, cbb, cn32, partials);
  post_kernel<2><<<256, 256, 0, stream>>>(partials, x, cbs, cn32, idx_f);
  resupd_kernel<<<2048, 256, 0, stream>>>((const float4*)x, cbs, idx_f,
                                          (ushort4*)res, 3);

  score_gemm<3><<<4096, 256, 0, stream>>>(res, cbb, cn32, partials);
  post_kernel<3><<<256, 256, 0, stream>>>(partials, x, cbs, cn32, idx_f);

  finalize_kernel<<<4096, 256, 0, stream>>>((const float4*)x, cbs, idx_f,
                                            (float4*)d_out, loss);
  write_losses_kernel<<<1, 64, 0, stream>>>(loss, out_f);
}

// Round 12
// 907.195 us; speedup vs baseline: 1.0163x; 1.0163x over previous
//
#include <hip/hip_runtime.h>

// ResidualVectorQuantizer on MI355X (gfx950) — XCD-grouped bf16-MFMA GEMM
// (128x128x32, 2-slot ring, stage-ahead + counted vmcnt(4), 0-conflict
// swizzle, 32KB LDS, 4 blocks/CU) + fused post (combine top-4 + margin +
// LDS-queued exact np-fp32 refine) + standalone streaming resupd + fused
// prep (incl. loss zeroing).
// Mapped design space (this session):
//  - blocks/CU x barriers/K-step: 4x2=119us (BEST), 3x1=129, 2x2=139, 2x1=149
//  - 5 blocks/CU spills acc[4][4] -> 1 GB scratch (R6)
//  - high-VGPR refine fused with streaming resupd -> 10% occupancy (R9)
//  - margin-test removal -> 262144 exact chains, 660 MB/level (R5)
// inputs:   d_in[0] = inputs    float32 [16,4096,512]  -> 65536 x 512
//           d_in[1] = codebooks float32 [4,1024,512]
// outputs (float32, concatenated flat):
//   [0 .. 33554431]          final_ste   (region doubles as scratch pre-finalize)
//   [33554432]               total_q_loss / 4
//   [33554433]               total_e_loss / 4
//   [33554434 .. +262143]    indices [4][16][4096] stored as float
// ws: [0,4MB) cb_bf16; [4MB,+64MB) res_bf16; [68MB,+16KB) cn32; +32B loss

#define NROWS 65536
#define DDIM  512
#define KC    1024

#define AS1 __attribute__((address_space(1)))
#define AS3 __attribute__((address_space(3)))

typedef __attribute__((ext_vector_type(8))) short short8v;
typedef __attribute__((ext_vector_type(4))) float f32x4;

__device__ __forceinline__ unsigned short f2bf(float f) {
  unsigned u = __float_as_uint(f);
  unsigned r = (u + 0x7FFFu + ((u >> 16) & 1u)) >> 16;
  return (unsigned short)r;
}

__device__ __forceinline__ bool lexlt(float v1, int i1, float v2, int i2) {
  return (v1 < v2) || (v1 == v2 && i1 < i2);
}

__device__ __forceinline__ void merge3(float& v0, float& v1, float& v2,
                                       float m0, float m1, float m2) {
  float x1 = fmaxf(v0, m0); v0 = fminf(v0, m0);
  float y = fminf(v1, m1), z = fmaxf(v1, m1);
  float nv1 = fminf(x1, y);
  v2 = fminf(fmaxf(x1, y), fminf(z, fminf(v2, m2)));
  v1 = nv1;
}

__device__ __forceinline__ void top3of4(float k0, float k1, float k2, float k3,
                                        float& m0, float& m1, float& m2) {
  float a = fminf(k0, k1), b = fmaxf(k0, k1);
  float c = fminf(k2, k3), d = fmaxf(k2, k3);
  m0 = fminf(a, c);
  float f = fmaxf(a, c), g = fminf(b, d);
  m1 = fminf(f, g); m2 = fmaxf(f, g);
}

// compiler-fence-wrapped workgroup barrier: raw s_barrier (no implicit
// vmcnt/lgkmcnt drain) with "memory" clobbers pinning LDS/global ops.
__device__ __forceinline__ void wg_barrier() {
  asm volatile("" ::: "memory");
  __builtin_amdgcn_s_barrier();
  asm volatile("" ::: "memory");
}

// ---------------- fused prep: cnorm + codebook cvt + initial residual ------
__global__ void __launch_bounds__(256)
prep_kernel(const float* __restrict__ cbs, float* __restrict__ cn32,
            const float4* __restrict__ x4, ushort4* __restrict__ cbb4,
            ushort4* __restrict__ res4, double* __restrict__ loss_acc) {
  const int code = blockIdx.x;           // 0..4095
  const int l = threadIdx.x;
  if (l < 32) {
    const int b = l >> 3, j = l & 7;
    const float* p = cbs + (size_t)code * DDIM + b * 128 + j;
    float racc;
    {
      #pragma clang fp contract(off)
      float x0 = p[0];
      racc = x0 * x0;
      for (int s = 1; s < 16; ++s) { float x = p[8 * s]; float sq = x * x; racc = racc + sq; }
    }
    {
      #pragma clang fp contract(off)
      float o;
      o = __shfl_xor(racc, 1, 64);  racc = racc + o;
      o = __shfl_xor(racc, 2, 64);  racc = racc + o;
      o = __shfl_xor(racc, 4, 64);  racc = racc + o;
      o = __shfl_xor(racc, 8, 64);  racc = racc + o;
      o = __shfl_xor(racc, 16, 64); racc = racc + o;
      if (l == 0) cn32[code] = racc;
    }
  }
  if (blockIdx.x == 0 && l >= 32 && l < 36) loss_acc[l - 32] = 0.0;
  const float4* cb4 = (const float4*)cbs;
  for (long i = blockIdx.x * 256L + threadIdx.x; i < 524288L;
       i += (long)gridDim.x * 256) {
    float4 v = cb4[i];
    ushort4 o; o.x = f2bf(v.x); o.y = f2bf(v.y); o.z = f2bf(v.z); o.w = f2bf(v.w);
    cbb4[i] = o;
  }
  for (long i = blockIdx.x * 256L + threadIdx.x; i < 8388608L;
       i += (long)gridDim.x * 256) {
    float4 v = x4[i];
    ushort4 o; o.x = f2bf(v.x); o.y = f2bf(v.y); o.z = f2bf(v.z); o.w = f2bf(v.w);
    res4[i] = o;
  }
}

// residual update, one WAVE per row: res = bf16( x - sum_{l<nlev} cb[idx_l] ),
// exact fp32 chain; indices read once per row (wave-uniform). Low-VGPR
// streaming kernel — keep separate from the high-VGPR refine (R9 lesson).
__global__ void __launch_bounds__(256)
resupd_kernel(const float4* __restrict__ x4, const float* __restrict__ cbs,
              const float* __restrict__ idx_f, ushort4* __restrict__ res4,
              int nlev) {
  const int gwave = (blockIdx.x * 256 + threadIdx.x) >> 6;
  const int lane  = threadIdx.x & 63;
  const int nwaves = gridDim.x * 4;
  const float4* cb4 = (const float4*)cbs;
  for (int row = gwave; row < NROWS; row += nwaves) {
    int ci[4];
    for (int l = 0; l < nlev; ++l) ci[l] = (int)idx_f[(size_t)l * NROWS + row];
    #pragma unroll
    for (int half = 0; half < 2; ++half) {
      const int p = half * 64 + lane;
      float4 v = x4[(size_t)row * 128 + p];
      for (int l = 0; l < nlev; ++l) {
        const float4 c = cb4[((size_t)(l * KC + ci[l])) * 128 + p];
        v.x -= c.x; v.y -= c.y; v.z -= c.z; v.w -= c.w;
      }
      ushort4 o; o.x = f2bf(v.x); o.y = f2bf(v.y); o.z = f2bf(v.z); o.w = f2bf(v.w);
      res4[(size_t)row * 128 + p] = o;
    }
  }
}

// ---------------- score GEMM (128x128x32, 2-slot ring, XCD-grouped) --------
// R8-exact champion: 118.5-119 us/dispatch, MfmaUtil ~25%, conflicts 0.
// 4 blocks/CU is the register-capped max (VGPR 64 + AGPR 64 per wave).
template <int LVL>
__global__ void __launch_bounds__(256, 4)
score_gemm(const ushort* __restrict__ res, const ushort* __restrict__ cbb,
           const float* __restrict__ cn32, float* __restrict__ partials) {
  __shared__ ushort lds[16384];   // 32 KB: At[2] @0/4096, Bt[2] @8192/12288

  const int t = threadIdx.x;
  const int w = t >> 6, lane = t & 63;
  const int fr = lane & 15, kg = lane >> 4;
  const int rh = w >> 1, ch = w & 1;
  const int xcd = blockIdx.x & 7;
  const int j   = blockIdx.x >> 3;
  const int colTile = j & 7;
  const int rowTile = xcd * 64 + (j >> 3);
  const int row0 = rowTile * 128;

  const ushort* Asrc = res + (size_t)row0 * DDIM;
  const ushort* Bsrc = cbb + ((size_t)LVL * KC + colTile * 128) * DDIM;

  const int r0s = t >> 2, kq = t & 3;
  const int r1s = 64 + r0s;
  const int swz = (t >> 3) & 3;
  const size_t off0 = (size_t)r0s * DDIM + (size_t)((kq ^ swz) * 8);
  const size_t off1 = (size_t)r1s * DDIM + (size_t)((kq ^ swz) * 8);
  const int kgs = (kg ^ ((fr >> 1) & 3)) * 8;

  f32x4 acc[4][4];
  #pragma unroll
  for (int ri = 0; ri < 4; ++ri)
    #pragma unroll
    for (int ci = 0; ci < 4; ++ci) { f32x4 z = {0.f, 0.f, 0.f, 0.f}; acc[ri][ci] = z; }

#define STG(KS, BI)                                                           \
  do {                                                                        \
    __builtin_amdgcn_global_load_lds(                                         \
        (const AS1 unsigned*)(Asrc + off0 + (KS) * 32),                       \
        (AS3 unsigned*)&lds[(BI) * 4096 + w * 512], 16, 0, 0);                \
    __builtin_amdgcn_global_load_lds(                                         \
        (const AS1 unsigned*)(Asrc + off1 + (KS) * 32),                       \
        (AS3 unsigned*)&lds[(BI) * 4096 + 2048 + w * 512], 16, 0, 0);         \
    __builtin_amdgcn_global_load_lds(                                         \
        (const AS1 unsigned*)(Bsrc + off0 + (KS) * 32),                       \
        (AS3 unsigned*)&lds[8192 + (BI) * 4096 + w * 512], 16, 0, 0);         \
    __builtin_amdgcn_global_load_lds(                                         \
        (const AS1 unsigned*)(Bsrc + off1 + (KS) * 32),                       \
        (AS3 unsigned*)&lds[8192 + (BI) * 4096 + 2048 + w * 512], 16, 0, 0);  \
  } while (0)

  STG(0, 0);
  #pragma unroll
  for (int ks = 0; ks < 16; ++ks) {
    const int cur = ks & 1;
    if (ks < 15) {
      STG(ks + 1, !cur);
      asm volatile("s_waitcnt vmcnt(4)" ::: "memory");
    } else {
      asm volatile("s_waitcnt vmcnt(0)" ::: "memory");
    }
    wg_barrier();
    short8v a[4], b[4];
    #pragma unroll
    for (int i = 0; i < 4; ++i)
      a[i] = *(const short8v*)&lds[cur * 4096 + (rh * 64 + i * 16 + fr) * 32 + kgs];
    #pragma unroll
    for (int i = 0; i < 4; ++i)
      b[i] = *(const short8v*)&lds[8192 + cur * 4096 + (ch * 64 + i * 16 + fr) * 32 + kgs];
    __builtin_amdgcn_s_setprio(1);
    #pragma unroll
    for (int ri = 0; ri < 4; ++ri)
      #pragma unroll
      for (int ci = 0; ci < 4; ++ci)
        acc[ri][ci] = __builtin_amdgcn_mfma_f32_16x16x32_bf16(
            a[ri], b[ci], acc[ri][ci], 0, 0, 0);
    __builtin_amdgcn_s_setprio(0);
    wg_barrier();
  }
#undef STG

  // ---- epilogue: scores -> packed keys -> per-row top-3 over 128 cols ----
  float* hT = (float*)lds;                 // [2 rh][2 ch][64][3] = 3 KB alias
  float cnv[4];
  #pragma unroll
  for (int ci = 0; ci < 4; ++ci)
    cnv[ci] = cn32[LVL * KC + colTile * 128 + ch * 64 + ci * 16 + fr] + 0.25f;

  #pragma unroll
  for (int ri = 0; ri < 4; ++ri) {
    #pragma unroll
    for (int j2 = 0; j2 < 4; ++j2) {
      float k[4];
      #pragma unroll
      for (int ci = 0; ci < 4; ++ci) {
        float s = fmaf(-2.0f, acc[ri][ci][j2], cnv[ci]);   // score + 0.25
        unsigned col = (unsigned)(colTile * 128 + ch * 64 + ci * 16 + fr);
        unsigned u = (__float_as_uint(s) & 0xFFFFFC00u) | col;
        k[ci] = __uint_as_float(u);
      }
      float m0, m1, m2;
      top3of4(k[0], k[1], k[2], k[3], m0, m1, m2);
      #pragma unroll
      for (int m = 1; m <= 8; m <<= 1) {
        float t0 = __shfl_xor(m0, m, 64);
        float t1 = __shfl_xor(m1, m, 64);
        float t2 = __shfl_xor(m2, m, 64);
        merge3(m0, m1, m2, t0, t1, t2);
      }
      if (fr == 0) {
        int row64 = ri * 16 + kg * 4 + j2;
        hT[(((rh * 2 + ch) * 64) + row64) * 3 + 0] = m0;
        hT[(((rh * 2 + ch) * 64) + row64) * 3 + 1] = m1;
        hT[(((rh * 2 + ch) * 64) + row64) * 3 + 2] = m2;
      }
    }
  }
  __syncthreads();

  if (t < 128) {
    const int lrh = t >> 6, r64 = t & 63;
    float u0 = hT[(((lrh * 2 + 0) * 64) + r64) * 3 + 0];
    float u1 = hT[(((lrh * 2 + 0) * 64) + r64) * 3 + 1];
    float u2 = hT[(((lrh * 2 + 0) * 64) + r64) * 3 + 2];
    float s0 = hT[(((lrh * 2 + 1) * 64) + r64) * 3 + 0];
    float s1 = hT[(((lrh * 2 + 1) * 64) + r64) * 3 + 1];
    float s2 = hT[(((lrh * 2 + 1) * 64) + r64) * 3 + 2];
    merge3(u0, u1, u2, s0, s1, s2);
    const int grow = row0 + lrh * 64 + r64;
    partials[(size_t)(colTile * 3 + 0) * NROWS + grow] = u0;
    partials[(size_t)(colTile * 3 + 1) * NROWS + grow] = u1;
    partials[(size_t)(colTile * 3 + 2) * NROWS + grow] = u2;
  }
}

// ---------------- post: combine (top-4 + margin) + LDS-queued refine -------
// 256 blocks x 256 rows (R8 structure — measured best). High VGPR is fine
// here: per-block work is tiny and there is no streaming phase.
template <int LVL>
__global__ void __launch_bounds__(256)
post_kernel(const float* __restrict__ partials, const float* __restrict__ x,
            const float* __restrict__ cbs, const float* __restrict__ cn32,
            float* __restrict__ idx_io) {
  __shared__ int qlist[256];
  __shared__ int qcL[256][4];
  __shared__ int qn_l;
  const int t = threadIdx.x;
  if (t == 0) qn_l = 0;
  __syncthreads();

  // ---- phase 1: combine ----
  const int row = blockIdx.x * 256 + t;
  {
    float v0 = 3.4e38f, v1 = 3.4e38f, v2 = 3.4e38f, v3 = 3.4e38f;
    #pragma unroll
    for (int p = 0; p < 24; ++p) {
      const float kv = partials[(size_t)p * NROWS + row];
      const bool b3 = kv < v3, b2 = kv < v2, b1 = kv < v1, b0 = kv < v0;
      v3 = b3 ? (b2 ? v2 : kv) : v3;
      v2 = b2 ? (b1 ? v1 : kv) : v2;
      v1 = b1 ? (b0 ? v0 : kv) : v1;
      v0 = b0 ? kv : v0;
    }
    if (v1 - v0 > 1e-3f) {
      idx_io[(size_t)LVL * NROWS + row] = (float)(__float_as_uint(v0) & 1023u);
    } else {
      int pos = atomicAdd(&qn_l, 1);
      qlist[pos] = row;
      qcL[pos][0] = (int)(__float_as_uint(v0) & 1023u);
      qcL[pos][1] = (int)(__float_as_uint(v1) & 1023u);
      qcL[pos][2] = (int)(__float_as_uint(v2) & 1023u);
      qcL[pos][3] = (int)(__float_as_uint(v3) & 1023u);
    }
  }
  __syncthreads();

  // ---- phase 2: exact np-fp32 refine of queued rows ----
  const int qn = qn_l;
  const float4* x4  = (const float4*)x;
  const float4* cb4 = (const float4*)cbs;
  const float*  cnL = cn32 + LVL * KC;

  for (int base = 0; base < qn * 4; base += 256) {
    const int wi = base + t;
    if (wi < qn * 4) {
      const int qi = wi >> 2, cd = wi & 3;
      const int grow = qlist[qi];
      const int ci   = qcL[qi][cd];
      const float4* xr = x4 + (size_t)grow * 128;
      const float4* cq = cb4 + ((size_t)LVL * KC + ci) * 128;
      const float4* cl[LVL > 0 ? LVL : 1];
      #pragma unroll
      for (int l = 0; l < LVL; ++l)
        cl[l] = cb4 +
                ((size_t)(l * KC + (int)idx_io[(size_t)l * NROWS + grow])) * 128;

      float Bk[4];
      float dacc = 0.0f;
      #pragma unroll
      for (int b = 0; b < 4; ++b) {
        #pragma clang fp contract(off)
        float racc[8];
        for (int s = 0; s < 16; ++s) {
          const int q = b * 32 + s * 2;
          float4 v0 = xr[q], v1 = xr[q + 1];
          #pragma unroll
          for (int l = 0; l < LVL; ++l) {
            const float4 c0 = cl[l][q], c1 = cl[l][q + 1];
            v0.x -= c0.x; v0.y -= c0.y; v0.z -= c0.z; v0.w -= c0.w;
            v1.x -= c1.x; v1.y -= c1.y; v1.z -= c1.z; v1.w -= c1.w;
          }
          if (s == 0) {
            racc[0] = v0.x * v0.x; racc[1] = v0.y * v0.y;
            racc[2] = v0.z * v0.z; racc[3] = v0.w * v0.w;
            racc[4] = v1.x * v1.x; racc[5] = v1.y * v1.y;
            racc[6] = v1.z * v1.z; racc[7] = v1.w * v1.w;
          } else {
            float sq;
            sq = v0.x * v0.x; racc[0] = racc[0] + sq;
            sq = v0.y * v0.y; racc[1] = racc[1] + sq;
            sq = v0.z * v0.z; racc[2] = racc[2] + sq;
            sq = v0.w * v0.w; racc[3] = racc[3] + sq;
            sq = v1.x * v1.x; racc[4] = racc[4] + sq;
            sq = v1.y * v1.y; racc[5] = racc[5] + sq;
            sq = v1.z * v1.z; racc[6] = racc[6] + sq;
            sq = v1.w * v1.w; racc[7] = racc[7] + sq;
          }
          const float4 c0 = cq[q], c1 = cq[q + 1];
          dacc = fmaf(v0.x, c0.x, dacc); dacc = fmaf(v0.y, c0.y, dacc);
          dacc = fmaf(v0.z, c0.z, dacc); dacc = fmaf(v0.w, c0.w, dacc);
          dacc = fmaf(v1.x, c1.x, dacc); dacc = fmaf(v1.y, c1.y, dacc);
          dacc = fmaf(v1.z, c1.z, dacc); dacc = fmaf(v1.w, c1.w, dacc);
        }
        float t0 = (racc[0] + racc[1]) + (racc[2] + racc[3]);
        float t1 = (racc[4] + racc[5]) + (racc[6] + racc[7]);
        Bk[b] = t0 + t1;
      }
      float vfin;
      {
        #pragma clang fp contract(off)
        float Arow = (Bk[0] + Bk[1]) + (Bk[2] + Bk[3]);
        float ab = Arow + cnL[ci];
        vfin = ab - 2.0f * dacc;
      }
      // quad lex-min: lanes 4k..4k+3 hold cands 0..3 of row grow
      float bv = vfin; int bi = ci;
      float ov = __shfl_xor(bv, 1, 64); int oi = __shfl_xor(bi, 1, 64);
      if (lexlt(ov, oi, bv, bi)) { bv = ov; bi = oi; }
      ov = __shfl_xor(bv, 2, 64); oi = __shfl_xor(bi, 2, 64);
      if (lexlt(ov, oi, bv, bi)) { bv = ov; bi = oi; }
      if (cd == 0) idx_io[(size_t)LVL * NROWS + grow] = (float)bi;
    }
  }
}

// ---------------- finalize: one wave per row ----------------
__global__ void __launch_bounds__(256)
finalize_kernel(const float4* __restrict__ x4, const float* __restrict__ cbs,
                const float* __restrict__ idx_f, float4* __restrict__ out,
                double* __restrict__ loss_acc) {
  double ls0 = 0.0, ls1 = 0.0, ls2 = 0.0, ls3 = 0.0;
  const int gwave = (blockIdx.x * 256 + threadIdx.x) >> 6;
  const int lane  = threadIdx.x & 63;
  const int nwaves = gridDim.x * 4;
  const float4* cb4 = (const float4*)cbs;

  for (int row = gwave; row < NROWS; row += nwaves) {
    int ci[4];
    #pragma unroll
    for (int l = 0; l < 4; ++l) ci[l] = (int)idx_f[(size_t)l * NROWS + row];
    #pragma unroll
    for (int half = 0; half < 2; ++half) {
      const int p = half * 64 + lane;
      const float4 xv = x4[(size_t)row * 128 + p];
      float4 rr = xv;
      float4 tq = make_float4(0.f, 0.f, 0.f, 0.f);
      #pragma unroll
      for (int l = 0; l < 4; ++l) {
        const float4 qv = cb4[((size_t)(l * KC + ci[l])) * 128 + p];
        rr.x -= qv.x; rr.y -= qv.y; rr.z -= qv.z; rr.w -= qv.w;
        const double ss = (double)rr.x * rr.x + (double)rr.y * rr.y +
                          (double)rr.z * rr.z + (double)rr.w * rr.w;
        if      (l == 0) ls0 += ss;
        else if (l == 1) ls1 += ss;
        else if (l == 2) ls2 += ss;
        else             ls3 += ss;
        tq.x += qv.x; tq.y += qv.y; tq.z += qv.z; tq.w += qv.w;
      }
      float4 o;
      o.x = xv.x + (tq.x - xv.x);
      o.y = xv.y + (tq.y - xv.y);
      o.z = xv.z + (tq.z - xv.z);
      o.w = xv.w + (tq.w - xv.w);
      out[(size_t)row * 128 + p] = o;
    }
  }
  #pragma unroll
  for (int m = 1; m <= 32; m <<= 1) {
    ls0 += __shfl_xor(ls0, m, 64);
    ls1 += __shfl_xor(ls1, m, 64);
    ls2 += __shfl_xor(ls2, m, 64);
    ls3 += __shfl_xor(ls3, m, 64);
  }
  __shared__ double sred[4][4];
  const int wave = threadIdx.x >> 6;
  if ((threadIdx.x & 63) == 0) {
    sred[wave][0] = ls0; sred[wave][1] = ls1; sred[wave][2] = ls2; sred[wave][3] = ls3;
  }
  __syncthreads();
  if (threadIdx.x < 4) {
    const double v = sred[0][threadIdx.x] + sred[1][threadIdx.x] +
                     sred[2][threadIdx.x] + sred[3][threadIdx.x];
    atomicAdd(loss_acc + threadIdx.x, v);
  }
}

__global__ void write_losses_kernel(const double* __restrict__ loss_acc,
                                    float* __restrict__ out) {
  if (threadIdx.x == 0 && blockIdx.x == 0) {
    const double inv = 1.0 / (double)((size_t)NROWS * (size_t)DDIM);
    const double tv = (loss_acc[0] * inv + loss_acc[1] * inv +
                       loss_acc[2] * inv + loss_acc[3] * inv) * 0.25;
    out[33554432] = (float)tv;
    out[33554433] = (float)tv;
  }
}

extern "C" void kernel_launch(void* const* d_in, const int* in_sizes, int n_in,
                              void* d_out, int out_size, void* d_ws, size_t ws_size,
                              hipStream_t stream) {
  (void)in_sizes; (void)n_in; (void)out_size; (void)ws_size;
  const float* x   = (const float*)d_in[0];
  const float* cbs = (const float*)d_in[1];
  float* out_f     = (float*)d_out;
  float* idx_f     = out_f + 33554434;

  ushort* cbb  = (ushort*)d_ws;                               // 4 MB
  ushort* res  = (ushort*)((char*)d_ws + 4194304);            // 64 MB
  float*  cn32 = (float*)((char*)d_ws + 4194304 + 67108864);  // 16 KB
  double* loss = (double*)((char*)d_ws + 4194304 + 67108864 + 16384);

  // scratch carved from the ste region of d_out (unused until finalize)
  float* partials = out_f;                        // 24 * 65536 floats = 6 MB

  prep_kernel<<<4096, 256, 0, stream>>>(cbs, cn32, (const float4*)x,
                                        (ushort4*)cbb, (ushort4*)res, loss);

  score_gemm<0><<<4096, 256, 0, stream>>>(res, cbb, cn32, partials);
  post_kernel<0><<<256, 256, 0, stream>>>(partials, x, cbs, cn32, idx_f);
  resupd_kernel<<<2048, 256, 0, stream>>>((const float4*)x, cbs, idx_f,
                                          (ushort4*)res, 1);

  score_gemm<1><<<4096, 256, 0, stream>>>(res, cbb, cn32, partials);
  post_kernel<1><<<256, 256, 0, stream>>>(partials, x, cbs, cn32, idx_f);
  resupd_kernel<<<2048, 256, 0, stream>>>((const float4*)x, cbs, idx_f,
                                          (ushort4*)res, 2);

  score_gemm<2><<<4096, 256, 0, stream>>>(res, cbb, cn32, partials);
  post_kernel<2><<<256, 256, 0, stream>>>(partials, x, cbs, cn32, idx_f);
  resupd_kernel<<<2048, 256, 0, stream>>>((const float4*)x, cbs, idx_f,
                                          (ushort4*)res, 3);

  score_gemm<3><<<4096, 256, 0, stream>>>(res, cbb, cn32, partials);
  post_kernel<3><<<256, 256, 0, stream>>>(partials, x, cbs, cn32, idx_f);

  finalize_kernel<<<2048, 256, 0, stream>>>((const float4*)x, cbs, idx_f,
                                            (float4*)d_out, loss);
  write_losses_kernel<<<1, 64, 0, stream>>>(loss, out_f);
}